// Round 3
// baseline (429.442 us; speedup 1.0000x reference)
//
#include <hip/hip_runtime.h>

using u16 = unsigned short;
using u32 = unsigned int;

typedef __attribute__((ext_vector_type(8))) __bf16 bf16x8;
typedef __attribute__((ext_vector_type(4))) float f32x4;
typedef __attribute__((ext_vector_type(16))) float f32x16;

#define DEVI __device__ __forceinline__

DEVI float bf2f(u16 u) {
  union { u32 i; float f; } v; v.i = ((u32)u) << 16; return v.f;
}
DEVI u16 f2bf(float f) {
  union { float f; u32 u; } v; v.f = f;
  u32 u = v.u;
  u32 r = (u + 0x7fffu + ((u >> 16) & 1u)) >> 16;
  return (u16)r;
}
// pack two f32 -> one u32 of 2x bf16 (compiler emits v_cvt_pk_bf16_f32)
DEVI u32 pkbf(float a, float b) {
  union { __bf16 h[2]; u32 u; } t;
  t.h[0] = (__bf16)a; t.h[1] = (__bf16)b;
  return t.u;
}

// async global->LDS, 16B per lane. LDS dest = wave-uniform base + lane*16.
DEVI void gload16(const u16* g, u16* l) {
  __builtin_amdgcn_global_load_lds(
      (const __attribute__((address_space(1))) void*)g,
      (__attribute__((address_space(3))) void*)l, 16, 0, 0);
}

// ---------------- cvt x: fp32 -> bf16, 8 elems/thread ----------------
__global__ __launch_bounds__(256) void cvt_bf16_f32(const float* __restrict__ in,
                                                    u16* __restrict__ out, int n8) {
  int i = blockIdx.x * 256 + threadIdx.x;
  if (i >= n8) return;
  const float4* fin = (const float4*)in;
  float4 a = fin[i * 2], b = fin[i * 2 + 1];
  u16 o[8] = {f2bf(a.x), f2bf(a.y), f2bf(a.z), f2bf(a.w),
              f2bf(b.x), f2bf(b.y), f2bf(b.z), f2bf(b.w)};
  ((uint4*)out)[i] = *(const uint4*)o;
}

// ------- transpose+convert: in[R][Cc] fp32 -> out[Cc][R] bf16 -------
__global__ __launch_bounds__(256) void transpose_cvt(const float* __restrict__ in,
                                                     u16* __restrict__ out,
                                                     int R, int Cc) {
  __shared__ u16 tile[32][33];
  int c0 = blockIdx.x * 32, r0 = blockIdx.y * 32;
  int x  = threadIdx.x & 31;
  int y0 = threadIdx.x >> 5;
  for (int yy = y0; yy < 32; yy += 8)
    tile[yy][x] = f2bf(in[(size_t)(r0 + yy) * Cc + c0 + x]);
  __syncthreads();
  for (int yy = y0; yy < 32; yy += 8)
    out[(size_t)(c0 + yy) * R + r0 + x] = tile[x][yy];
}

// ---- transpose bf16 with input row-stride (for V slice of QKV) ----
__global__ __launch_bounds__(256) void transpose_sl(const u16* __restrict__ in, int ldin,
                                                    u16* __restrict__ out,
                                                    int R, int Cc) {
  __shared__ u16 tile[32][33];
  int c0 = blockIdx.x * 32, r0 = blockIdx.y * 32;
  int x  = threadIdx.x & 31;
  int y0 = threadIdx.x >> 5;
  for (int yy = y0; yy < 32; yy += 8)
    tile[yy][x] = in[(size_t)(r0 + yy) * ldin + c0 + x];
  __syncthreads();
  for (int yy = y0; yy < 32; yy += 8)
    out[(size_t)(c0 + yy) * R + r0 + x] = tile[x][yy];
}

// ---------------- RoPE in place on a Q/K slice (row stride ld) ----------------
__global__ __launch_bounds__(256) void rope_k(u16* __restrict__ X, int ld, int width, int total) {
  int idx = blockIdx.x * 256 + threadIdx.x;
  if (idx >= total) return;
  int ppr  = width >> 1;
  int row  = idx / ppr;
  int rem  = idx - row * ppr;
  int head = rem >> 5;
  int d    = rem & 31;
  int t    = row & 2047;
  float inv = exp2f(-(float)d * 0.59161152f);  // 500000^(-d/32)
  float ang = (float)t * inv;
  float s, c;
  sincosf(ang, &s, &c);
  size_t base = (size_t)row * ld + head * 64 + d;
  float x0 = bf2f(X[base]);
  float x1 = bf2f(X[base + 32]);
  X[base]      = f2bf(x0 * c - x1 * s);
  X[base + 32] = f2bf(x1 * c + x0 * s);
}

// ---- m97-style GEMM: C[M,N] = A[M,K] * Bt[N,K]^T, 128x128 tile, BK=32 ----
DEVI void cstore(u16* C, size_t idx, float v)   { C[idx] = f2bf(v); }
DEVI void cstore(float* C, size_t idx, float v) { C[idx] = v; }

template <typename TO>
__global__ __launch_bounds__(256) void gemm128(const u16* __restrict__ A,
                                               const u16* __restrict__ Bt,
                                               TO* __restrict__ C,
                                               int M, int N, int K) {
  __shared__ u16 As[128 * 32];
  __shared__ u16 Bs[128 * 32];
  int tid = threadIdx.x, wid = tid >> 6, lane = tid & 63;
  int quad = lane >> 4, l15 = lane & 15;
  int m0 = blockIdx.y * 128, n0 = blockIdx.x * 128;
  int wm = (wid >> 1) * 64, wn = (wid & 1) * 64;

  int r0s = wid * 16 + (lane >> 2);
  int r1s = 64 + wid * 16 + (lane >> 2);
  int cblk = lane & 3;
  int cs0 = (cblk ^ ((r0s >> 1) & 3)) * 8;
  int cs1 = (cblk ^ ((r1s >> 1) & 3)) * 8;
  u16* lA0 = As + wid * 512 + lane * 8;
  u16* lA1 = As + (4 + wid) * 512 + lane * 8;
  u16* lB0 = Bs + wid * 512 + lane * 8;
  u16* lB1 = Bs + (4 + wid) * 512 + lane * 8;
  const u16* gA0 = A + (size_t)(m0 + r0s) * K + cs0;
  const u16* gA1 = A + (size_t)(m0 + r1s) * K + cs1;
  const u16* gB0 = Bt + (size_t)(n0 + r0s) * K + cs0;
  const u16* gB1 = Bt + (size_t)(n0 + r1s) * K + cs1;

  f32x4 acc[4][4];
  for (int i = 0; i < 4; i++)
    for (int j = 0; j < 4; j++) acc[i][j] = f32x4{0.f, 0.f, 0.f, 0.f};

  for (int k0 = 0; k0 < K; k0 += 32) {
    __syncthreads();                 // prior iter's frag reads done
    gload16(gA0 + k0, lA0);
    gload16(gA1 + k0, lA1);
    gload16(gB0 + k0, lB0);
    gload16(gB1 + k0, lB1);
    __builtin_amdgcn_s_waitcnt(0x0F70);  // vmcnt(0): force async-LDS drain
    __syncthreads();
    bf16x8 af[4], bf_[4];
    for (int mi = 0; mi < 4; mi++) {
      int row = wm + mi * 16 + l15;
      af[mi] = *(const bf16x8*)(As + row * 32 + ((quad ^ ((row >> 1) & 3)) * 8));
    }
    for (int ni = 0; ni < 4; ni++) {
      int row = wn + ni * 16 + l15;
      bf_[ni] = *(const bf16x8*)(Bs + row * 32 + ((quad ^ ((row >> 1) & 3)) * 8));
    }
    for (int mi = 0; mi < 4; mi++)
      for (int ni = 0; ni < 4; ni++)
        acc[mi][ni] = __builtin_amdgcn_mfma_f32_16x16x32_bf16(af[mi], bf_[ni], acc[mi][ni], 0, 0, 0);
  }
  for (int mi = 0; mi < 4; mi++)
    for (int ni = 0; ni < 4; ni++)
      for (int r = 0; r < 4; r++) {
        int row = m0 + wm + mi * 16 + quad * 4 + r;
        int col = n0 + wn + ni * 16 + l15;
        cstore(C, (size_t)row * N + col, acc[mi][ni][r]);
      }
}

// ---------------- Flash attention v2: swapped-QK 32x32 MFMA ----------------
// Each wave owns 32 q-rows; 4 waves/block -> 128 q-rows/block.
// Per 32-key tile: S^T = mfma32x32x16(K,Q^T) (4x), in-register softmax,
// P handed to PV A-operand via cvt_pk + v_permlane32_swap (no LDS P tile),
// PV = mfma32x32x16(P, V) (4x). K staged via global_load_lds with
// XOR-swizzled source; V reg-staged to padded V^T tile. Double-buffered,
// ONE barrier per tile, vmcnt(0) only before the V ds_write.
//
// permlane semantics (CDNA4 ISA): v_permlane32_swap_b32 vdst, vsrc swaps
// rows 2-3 of VDST (lanes 32-63) with rows 0-1 of SRC (lanes 0-31):
//   vdst'[32:63] = vsrc_old[0:31];  vsrc'[0:31] = vdst_old[32:63].
// Needed: w0 = {lo: a01@lo=(0,1), hi: a45@lo=(8,9)},
//         w2 = {lo: a01@hi=(4,5), hi: a45@hi=(12,13)}.
// => swap(dst=a01, src=a45) gives a01'=w0, a45'=w2.  (Round-2's flipped
// order produced w0={lo:(12,13),hi:(4,5)} -> the observed absmax 5.78.)
__global__ __launch_bounds__(256) void attn32(const u16* __restrict__ QKV,
                                              const u16* __restrict__ Vt,
                                              u16* __restrict__ Y) {
  constexpr int VLD = 40;                 // V^T row pad: 80B stride, 16B aligned
  __shared__ u16 Ks[2 * 32 * 64];         // 2 bufs, [key][d] swizzled granules
  __shared__ u16 Vst[2 * 64 * VLD];       // 2 bufs, [d][key] padded

  int tid = threadIdx.x, wid = tid >> 6, lane = tid & 63;
  int l31 = lane & 31, hi = lane >> 5;
  int bh = blockIdx.y, b = bh >> 5, h = bh & 31, kvh = h >> 2;
  int q0b = blockIdx.x * 128;
  int q0w = q0b + wid * 32;
  int qg  = q0w + l31;                    // this lane's q row (local time idx)

  const float sc_log2e = 0.18033688f;     // (1/sqrt(64)) * log2(e)

  // Q fragments (Q already RoPE'd in place): Q[qg][dh*16 + hi*8 + i]
  bf16x8 qf[4];
  {
    const u16* qp = QKV + (size_t)(b * 2048 + qg) * 3072 + h * 64 + hi * 8;
#pragma unroll
    for (int dh = 0; dh < 4; dh++) qf[dh] = *(const bf16x8*)(qp + dh * 16);
  }

  // K staging: wave w stages rows w*8..w*8+7 of the 32-key tile.
  // LDS linear granule (lane&7) at row r holds K[r][((lane&7)^(r&7))*8 ..+7]
  int krow = wid * 8 + (lane >> 3);
  int kg   = lane & 7;
  const u16* gK = QKV + (size_t)(b * 2048 + krow) * 3072 + 2048 + kvh * 64
                + ((kg ^ (krow & 7)) * 8);
  u16* lK = Ks + wid * 512 + lane * 8;    // + buf*2048

  // V staging: thread t loads 16B of Vt row (t>>2), keys (t&3)*8
  int vr = tid >> 2, vc = (tid & 3) * 8;
  const u16* gV = Vt + (size_t)(kvh * 64 + vr) * 4096 + b * 2048 + vc;
  u16* lV = Vst + vr * VLD + vc;          // + buf*2560

  f32x16 o0, o1;
#pragma unroll
  for (int i = 0; i < 16; i++) { o0[i] = 0.f; o1[i] = 0.f; }
  float zsum = 0.f;

  int nkt = 4 * blockIdx.x + 4;           // cover keys 0 .. q0b+127

  // prologue: stage tile 0 into buf 0
  {
    uint4 vv = *(const uint4*)(gV);
    gload16(gK, lK);
    __builtin_amdgcn_s_waitcnt(0x0F70);   // vmcnt(0)
    *(uint4*)(lV) = vv;
  }
  __syncthreads();

  int cur = 0;
  for (int kt = 0; kt < nkt; kt++) {
    int kbase = kt * 32;
    int nxt = cur ^ 1;
    uint4 vv;
    bool more = (kt + 1 < nkt);
    if (more) {                           // issue next tile's loads early
      vv = *(const uint4*)(gV + (size_t)(kt + 1) * 32);
      gload16(gK + (size_t)(kt + 1) * 32 * 3072, lK + nxt * 2048);
    }

    if (kbase <= q0w + 31) {              // wave-uniform causal skip
      const u16* Kb = Ks + cur * 2048;
      const u16* Vb = Vst + cur * 2560;

      // S^T[key][q] = sum_d K[key][d] * Q[q][d]
      f32x16 s;
#pragma unroll
      for (int i = 0; i < 16; i++) s[i] = 0.f;
#pragma unroll
      for (int dh = 0; dh < 4; dh++) {
        int g = (dh * 2 + hi) ^ (l31 & 7);
        bf16x8 kf = *(const bf16x8*)(Kb + l31 * 64 + g * 8);
        s = __builtin_amdgcn_mfma_f32_32x32x16_bf16(kf, qf[dh], s, 0, 0, 0);
      }

      // softmax numerator, lane-local (q = l31, 16 keys in C-layout pattern)
      float p[16];
#pragma unroll
      for (int r = 0; r < 16; r++) {
        int key = kbase + (r & 3) + 8 * (r >> 2) + 4 * hi;
        float pv = (key <= qg) ? exp2f(s[r] * sc_log2e) : 0.f;
        zsum += pv;
        p[r] = pv;
      }

      // P -> PV A-fragment: cvt_pk pairs + permlane32_swap (hi<->lo halves)
#pragma unroll
      for (int kk = 0; kk < 2; kk++) {
        const float* pp = p + kk * 8;
        u32 a01 = pkbf(pp[0], pp[1]);
        u32 a23 = pkbf(pp[2], pp[3]);
        u32 a45 = pkbf(pp[4], pp[5]);
        u32 a67 = pkbf(pp[6], pp[7]);
        asm volatile("v_permlane32_swap_b32 %0, %1" : "+v"(a01), "+v"(a45));
        asm volatile("v_permlane32_swap_b32 %0, %1" : "+v"(a23), "+v"(a67));
        union { u32 w[4]; bf16x8 v; } pf;
        pf.w[0] = a01; pf.w[1] = a23; pf.w[2] = a45; pf.w[3] = a67;
        bf16x8 v0 = *(const bf16x8*)(Vb + (size_t)l31 * VLD + kk * 16 + hi * 8);
        bf16x8 v1 = *(const bf16x8*)(Vb + (size_t)(32 + l31) * VLD + kk * 16 + hi * 8);
        o0 = __builtin_amdgcn_mfma_f32_32x32x16_bf16(pf.v, v0, o0, 0, 0, 0);
        o1 = __builtin_amdgcn_mfma_f32_32x32x16_bf16(pf.v, v1, o1, 0, 0, 0);
      }
    }

    if (more) {
      __builtin_amdgcn_s_waitcnt(0x0F70); // vmcnt(0): K in LDS, V in regs
      *(uint4*)(lV + nxt * 2560) = vv;
    }
    __syncthreads();                      // ONE barrier per tile
    cur = nxt;
  }

  // row sums: lane and lane^32 hold complementary key-halves of q = l31
  float zf = zsum + __shfl_xor(zsum, 32);

  // write out: C rows are q = (r&3)+8*(r>>2)+4*hi, cols d = half*32 + l31
#pragma unroll
  for (int r = 0; r < 16; r++) {
    int qr = (r & 3) + 8 * (r >> 2) + 4 * hi;  // local q row 0..31
    float zr = __shfl(zf, qr, 64);
    float inv = 1.f / zr;
    size_t row = (size_t)(b * 2048 + q0w + qr);
    Y[row * 2048 + h * 64 + l31]      = f2bf(o0[r] * inv);
    Y[row * 2048 + h * 64 + 32 + l31] = f2bf(o1[r] * inv);
  }
}

extern "C" void kernel_launch(void* const* d_in, const int* in_sizes, int n_in,
                              void* d_out, int out_size, void* d_ws, size_t ws_size,
                              hipStream_t stream) {
  const float* x  = (const float*)d_in[0];  // [4096][2048] fp32
  const float* Wq = (const float*)d_in[1];  // [2048][2048]
  const float* Wk = (const float*)d_in[2];  // [2048][512]
  const float* Wv = (const float*)d_in[3];  // [2048][512]
  const float* Wo = (const float*)d_in[4];  // [2048][2048]
  float* outp = (float*)d_out;              // fp32 out

  // workspace (u16 units), ~59 MB peak
  u16* xb    = (u16*)d_ws;             // [4096][2048]   8388608
  u16* WqkvT = xb + 8388608;           // [3072][2048]   6291456
  u16* QKV   = WqkvT + 6291456;        // [4096][3072]  12582912
  u16* Vt    = QKV + 12582912;         // [512][4096]    2097152
  u16* Yb    = xb;                     // reuse (xb dead after QKV gemm)
  u16* WoT   = WqkvT;                  // reuse (WqkvT dead after QKV gemm)

  // x -> bf16
  cvt_bf16_f32<<<4096, 256, 0, stream>>>(x, xb, 1048576);

  // weights -> transposed bf16, stacked [Wq^T; Wk^T; Wv^T]
  transpose_cvt<<<dim3(64, 64), 256, 0, stream>>>(Wq, WqkvT, 2048, 2048);
  transpose_cvt<<<dim3(16, 64), 256, 0, stream>>>(Wk, WqkvT + (size_t)2048 * 2048, 2048, 512);
  transpose_cvt<<<dim3(16, 64), 256, 0, stream>>>(Wv, WqkvT + (size_t)2560 * 2048, 2048, 512);

  // fused QKV projection: [4096,2048] x [2048,3072] -> [4096,3072]
  gemm128<u16><<<dim3(24, 32), 256, 0, stream>>>(xb, WqkvT, QKV, 4096, 3072, 2048);

  // RoPE on Q and K slices (in place, strided)
  rope_k<<<(4096 * 1024) / 256, 256, 0, stream>>>(QKV, 3072, 2048, 4096 * 1024);
  rope_k<<<(4096 * 256) / 256, 256, 0, stream>>>(QKV + 2048, 3072, 512, 4096 * 256);

  // V slice -> V^T
  transpose_sl<<<dim3(16, 128), 256, 0, stream>>>(QKV + 2560, 3072, Vt, 4096, 512);

  // attention v2 (swapped-QK 32x32) -> Yb
  attn32<<<dim3(16, 64), 256, 0, stream>>>(QKV, Vt, Yb);

  // Wo -> WoT, output projection -> fp32 d_out
  transpose_cvt<<<dim3(64, 64), 256, 0, stream>>>(Wo, WoT, 2048, 2048);
  gemm128<float><<<dim3(16, 32), 256, 0, stream>>>(Yb, WoT, outp, 4096, 2048, 2048);
}

// Round 4
// 351.433 us; speedup vs baseline: 1.2220x; 1.2220x over previous
//
#include <hip/hip_runtime.h>

using u16 = unsigned short;
using u32 = unsigned int;

typedef __attribute__((ext_vector_type(8))) __bf16 bf16x8;
typedef __attribute__((ext_vector_type(4))) float f32x4;
typedef __attribute__((ext_vector_type(16))) float f32x16;

#define DEVI __device__ __forceinline__

DEVI float bf2f(u16 u) {
  union { u32 i; float f; } v; v.i = ((u32)u) << 16; return v.f;
}
DEVI u16 f2bf(float f) {
  union { float f; u32 u; } v; v.f = f;
  u32 u = v.u;
  u32 r = (u + 0x7fffu + ((u >> 16) & 1u)) >> 16;
  return (u16)r;
}
// pack two f32 -> one u32 of 2x bf16 (compiler emits v_cvt_pk_bf16_f32)
DEVI u32 pkbf(float a, float b) {
  union { __bf16 h[2]; u32 u; } t;
  t.h[0] = (__bf16)a; t.h[1] = (__bf16)b;
  return t.u;
}

// async global->LDS, 16B per lane. LDS dest = wave-uniform base + lane*16.
DEVI void gload16(const u16* g, u16* l) {
  __builtin_amdgcn_global_load_lds(
      (const __attribute__((address_space(1))) void*)g,
      (__attribute__((address_space(3))) void*)l, 16, 0, 0);
}

// ---------------- cvt x: fp32 -> bf16, 8 elems/thread ----------------
__global__ __launch_bounds__(256) void cvt_bf16_f32(const float* __restrict__ in,
                                                    u16* __restrict__ out, int n8) {
  int i = blockIdx.x * 256 + threadIdx.x;
  if (i >= n8) return;
  const float4* fin = (const float4*)in;
  float4 a = fin[i * 2], b = fin[i * 2 + 1];
  u16 o[8] = {f2bf(a.x), f2bf(a.y), f2bf(a.z), f2bf(a.w),
              f2bf(b.x), f2bf(b.y), f2bf(b.z), f2bf(b.w)};
  ((uint4*)out)[i] = *(const uint4*)o;
}

// ------- transpose+convert: in[R][Cc] fp32 -> out[Cc][R] bf16 -------
__global__ __launch_bounds__(256) void transpose_cvt(const float* __restrict__ in,
                                                     u16* __restrict__ out,
                                                     int R, int Cc) {
  __shared__ u16 tile[32][33];
  int c0 = blockIdx.x * 32, r0 = blockIdx.y * 32;
  int x  = threadIdx.x & 31;
  int y0 = threadIdx.x >> 5;
  for (int yy = y0; yy < 32; yy += 8)
    tile[yy][x] = f2bf(in[(size_t)(r0 + yy) * Cc + c0 + x]);
  __syncthreads();
  for (int yy = y0; yy < 32; yy += 8)
    out[(size_t)(c0 + yy) * R + r0 + x] = tile[x][yy];
}

// ---- transpose bf16 with input row-stride (for V slice of QKV) ----
__global__ __launch_bounds__(256) void transpose_sl(const u16* __restrict__ in, int ldin,
                                                    u16* __restrict__ out,
                                                    int R, int Cc) {
  __shared__ u16 tile[32][33];
  int c0 = blockIdx.x * 32, r0 = blockIdx.y * 32;
  int x  = threadIdx.x & 31;
  int y0 = threadIdx.x >> 5;
  for (int yy = y0; yy < 32; yy += 8)
    tile[yy][x] = in[(size_t)(r0 + yy) * ldin + c0 + x];
  __syncthreads();
  for (int yy = y0; yy < 32; yy += 8)
    out[(size_t)(c0 + yy) * R + r0 + x] = tile[x][yy];
}

// ---------------- RoPE in place on a Q/K slice (row stride ld) ----------------
__global__ __launch_bounds__(256) void rope_k(u16* __restrict__ X, int ld, int width, int total) {
  int idx = blockIdx.x * 256 + threadIdx.x;
  if (idx >= total) return;
  int ppr  = width >> 1;
  int row  = idx / ppr;
  int rem  = idx - row * ppr;
  int head = rem >> 5;
  int d    = rem & 31;
  int t    = row & 2047;
  float inv = exp2f(-(float)d * 0.59161152f);  // 500000^(-d/32)
  float ang = (float)t * inv;
  float s, c;
  sincosf(ang, &s, &c);
  size_t base = (size_t)row * ld + head * 64 + d;
  float x0 = bf2f(X[base]);
  float x1 = bf2f(X[base + 32]);
  X[base]      = f2bf(x0 * c - x1 * s);
  X[base + 32] = f2bf(x1 * c + x0 * s);
}

// ---- m97-style GEMM: C[M,N] = A[M,K] * Bt[N,K]^T, 128x128 tile, BK=32 ----
DEVI void cstore(u16* C, size_t idx, float v)   { C[idx] = f2bf(v); }
DEVI void cstore(float* C, size_t idx, float v) { C[idx] = v; }

template <typename TO>
__global__ __launch_bounds__(256) void gemm128(const u16* __restrict__ A,
                                               const u16* __restrict__ Bt,
                                               TO* __restrict__ C,
                                               int M, int N, int K) {
  __shared__ u16 As[128 * 32];
  __shared__ u16 Bs[128 * 32];
  int tid = threadIdx.x, wid = tid >> 6, lane = tid & 63;
  int quad = lane >> 4, l15 = lane & 15;
  int m0 = blockIdx.y * 128, n0 = blockIdx.x * 128;
  int wm = (wid >> 1) * 64, wn = (wid & 1) * 64;

  int r0s = wid * 16 + (lane >> 2);
  int r1s = 64 + wid * 16 + (lane >> 2);
  int cblk = lane & 3;
  int cs0 = (cblk ^ ((r0s >> 1) & 3)) * 8;
  int cs1 = (cblk ^ ((r1s >> 1) & 3)) * 8;
  u16* lA0 = As + wid * 512 + lane * 8;
  u16* lA1 = As + (4 + wid) * 512 + lane * 8;
  u16* lB0 = Bs + wid * 512 + lane * 8;
  u16* lB1 = Bs + (4 + wid) * 512 + lane * 8;
  const u16* gA0 = A + (size_t)(m0 + r0s) * K + cs0;
  const u16* gA1 = A + (size_t)(m0 + r1s) * K + cs1;
  const u16* gB0 = Bt + (size_t)(n0 + r0s) * K + cs0;
  const u16* gB1 = Bt + (size_t)(n0 + r1s) * K + cs1;

  f32x4 acc[4][4];
  for (int i = 0; i < 4; i++)
    for (int j = 0; j < 4; j++) acc[i][j] = f32x4{0.f, 0.f, 0.f, 0.f};

  for (int k0 = 0; k0 < K; k0 += 32) {
    __syncthreads();                 // prior iter's frag reads done
    gload16(gA0 + k0, lA0);
    gload16(gA1 + k0, lA1);
    gload16(gB0 + k0, lB0);
    gload16(gB1 + k0, lB1);
    __builtin_amdgcn_s_waitcnt(0x0F70);  // vmcnt(0): force async-LDS drain
    __syncthreads();
    bf16x8 af[4], bf_[4];
    for (int mi = 0; mi < 4; mi++) {
      int row = wm + mi * 16 + l15;
      af[mi] = *(const bf16x8*)(As + row * 32 + ((quad ^ ((row >> 1) & 3)) * 8));
    }
    for (int ni = 0; ni < 4; ni++) {
      int row = wn + ni * 16 + l15;
      bf_[ni] = *(const bf16x8*)(Bs + row * 32 + ((quad ^ ((row >> 1) & 3)) * 8));
    }
    for (int mi = 0; mi < 4; mi++)
      for (int ni = 0; ni < 4; ni++)
        acc[mi][ni] = __builtin_amdgcn_mfma_f32_16x16x32_bf16(af[mi], bf_[ni], acc[mi][ni], 0, 0, 0);
  }
  for (int mi = 0; mi < 4; mi++)
    for (int ni = 0; ni < 4; ni++)
      for (int r = 0; r < 4; r++) {
        int row = m0 + wm + mi * 16 + quad * 4 + r;
        int col = n0 + wn + ni * 16 + l15;
        cstore(C, (size_t)row * N + col, acc[mi][ni][r]);
      }
}

// ---------------- Flash attention v3: KVBLK=64 + causal pairing ----------------
// Round-3 post-mortem: v1 (16x16, 64 worst-case iters) and v2 (32x32, 64 worst
// iters) timed within 5% -> staging-iteration-bound, not compute-bound.
// v3: (a) 64 keys per stage iteration (half the vmcnt(0)+barrier rounds, 2x
// compute per iteration to hide the depth-1 prefetch); (b) causal load balance:
// block p handles q-strips jA=p and jB=15-p sequentially -> every block does
// exactly 2(jA+1)+2(jB+1) = 34 uniform iterations (was 4..64, 16:1 imbalance);
// (c) full/diagonal subtile split: causal cmp+cndmask only on the single
// diagonal subtile per wave per pass; (d) V tile XOR-granule swizzled like K.
// Compute body (swapped-QK 32x32, in-reg softmax, cvt_pk+permlane32_swap P
// hand-off) is verbatim from the round-3-verified kernel.
__global__ __launch_bounds__(256) void attn64(const u16* __restrict__ QKV,
                                              const u16* __restrict__ Vt,
                                              u16* __restrict__ Y) {
  __shared__ u16 Ks[2 * 64 * 64];   // 2 bufs, [key][d], granule-swizzled
  __shared__ u16 Vst[2 * 64 * 64];  // 2 bufs, [d][key], granule-swizzled

  int tid = threadIdx.x, wid = tid >> 6, lane = tid & 63;
  int l31 = lane & 31, hi = lane >> 5;
  int bh = blockIdx.y, b = bh >> 5, h = bh & 31, kvh = h >> 2;
  int p = blockIdx.x;                       // pair index 0..7

  const float sc_log2e = 0.18033688f;       // (1/sqrt(64)) * log2(e)

  // K staging (global_load_lds, linear dest + inverse-swizzled src):
  // wave w stages rows w*8..w*8+7 (and +32) of the 64-key tile.
  // LDS slot g at row r holds K[r][((g^(r&7))*8) ..+7].
  int kr  = wid * 8 + (lane >> 3);
  int kgn = lane & 7;
  const u16* gK0 = QKV + (size_t)(b * 2048 + kr) * 3072 + 2048 + kvh * 64
                 + ((kgn ^ (kr & 7)) * 8);
  u16* lK0 = Ks + wid * 512 + lane * 8;     // +buf*4096; +2048 for rows+32

  // V staging (reg-staged, swizzled ds_write): thread t handles d-rows
  // vr=t>>3 and vr+32, key-granule vg=t&7. Slot (vg^(d&7)) holds keys vg*8..+7.
  int vr = tid >> 3, vg = tid & 7;
  const u16* gV0 = Vt + (size_t)(kvh * 64 + vr) * 4096 + b * 2048 + vg * 8;
  u16* lV0 = Vst + vr * 64 + ((vg ^ (vr & 7)) * 8);  // +buf*4096; +2048 for d+32

  for (int pass = 0; pass < 2; pass++) {
    int j   = pass ? (15 - p) : p;          // q-strip index 0..15
    int q0w = j * 128 + wid * 32;
    int qg  = q0w + l31;                    // this lane's q row

    // Q fragments (RoPE'd in place): Q[qg][dh*16 + hi*8 + i]
    bf16x8 qf[4];
    {
      const u16* qp = QKV + (size_t)(b * 2048 + qg) * 3072 + h * 64 + hi * 8;
#pragma unroll
      for (int dh = 0; dh < 4; dh++) qf[dh] = *(const bf16x8*)(qp + dh * 16);
    }

    f32x16 o0, o1;
#pragma unroll
    for (int i = 0; i < 16; i++) { o0[i] = 0.f; o1[i] = 0.f; }
    float zsum = 0.f;

    int nkt = 2 * (j + 1);                  // 64-key tiles covering 0..j*128+127

    // prologue: stage tile 0 into buf 0
    {
      uint4 va = *(const uint4*)(gV0);
      uint4 vb = *(const uint4*)(gV0 + 32 * 4096);
      gload16(gK0, lK0);
      gload16(gK0 + 32 * 3072, lK0 + 2048);
      __builtin_amdgcn_s_waitcnt(0x0F70);   // vmcnt(0)
      *(uint4*)(lV0)        = va;
      *(uint4*)(lV0 + 2048) = vb;
    }
    __syncthreads();

    int cur = 0;
    for (int kt = 0; kt < nkt; kt++) {
      int kbase = kt * 64;
      int nxt = cur ^ 1;
      bool more = (kt + 1 < nkt);
      uint4 va, vb;
      if (more) {                           // issue next tile's loads early
        size_t ko = (size_t)(kbase + 64);
        va = *(const uint4*)(gV0 + ko);
        vb = *(const uint4*)(gV0 + 32 * 4096 + ko);
        gload16(gK0 + ko * 3072, lK0 + nxt * 4096);
        gload16(gK0 + ko * 3072 + 32 * 3072, lK0 + nxt * 4096 + 2048);
      }

      const u16* Kb = Ks + cur * 4096;
      const u16* Vb = Vst + cur * 4096;
#pragma unroll
      for (int sub = 0; sub < 2; sub++) {
        int kb = kbase + sub * 32;
        if (kb > q0w) break;                // wave-uniform causal skip

        // S^T[key][q] over keys kb..kb+31
        f32x16 s;
#pragma unroll
        for (int i = 0; i < 16; i++) s[i] = 0.f;
#pragma unroll
        for (int dh = 0; dh < 4; dh++) {
          int g = (dh * 2 + hi) ^ (l31 & 7);
          bf16x8 kf = *(const bf16x8*)(Kb + (sub * 32 + l31) * 64 + g * 8);
          s = __builtin_amdgcn_mfma_f32_32x32x16_bf16(kf, qf[dh], s, 0, 0, 0);
        }

        float pb[16];
        if (kb < q0w) {                     // full subtile: no mask needed
#pragma unroll
          for (int r = 0; r < 16; r++) {
            float pv = exp2f(s[r] * sc_log2e);
            zsum += pv;
            pb[r] = pv;
          }
        } else {                            // diagonal subtile (kb == q0w)
#pragma unroll
          for (int r = 0; r < 16; r++) {
            int key = kb + (r & 3) + 8 * (r >> 2) + 4 * hi;
            float pv = (key <= qg) ? exp2f(s[r] * sc_log2e) : 0.f;
            zsum += pv;
            pb[r] = pv;
          }
        }

        // P -> PV A-fragment: cvt_pk + permlane32_swap (verified round 3)
#pragma unroll
        for (int kk = 0; kk < 2; kk++) {
          const float* pp = pb + kk * 8;
          u32 a01 = pkbf(pp[0], pp[1]);
          u32 a23 = pkbf(pp[2], pp[3]);
          u32 a45 = pkbf(pp[4], pp[5]);
          u32 a67 = pkbf(pp[6], pp[7]);
          asm volatile("v_permlane32_swap_b32 %0, %1" : "+v"(a01), "+v"(a45));
          asm volatile("v_permlane32_swap_b32 %0, %1" : "+v"(a23), "+v"(a67));
          union { u32 w[4]; bf16x8 v; } pf;
          pf.w[0] = a01; pf.w[1] = a23; pf.w[2] = a45; pf.w[3] = a67;
          int kgr = sub * 4 + kk * 2 + hi;  // key granule within 64-key tile
          const u16* vp = Vb + l31 * 64 + ((kgr ^ (l31 & 7)) * 8);
          bf16x8 v0 = *(const bf16x8*)(vp);
          bf16x8 v1 = *(const bf16x8*)(vp + 2048);   // d+32 rows
          o0 = __builtin_amdgcn_mfma_f32_32x32x16_bf16(pf.v, v0, o0, 0, 0, 0);
          o1 = __builtin_amdgcn_mfma_f32_32x32x16_bf16(pf.v, v1, o1, 0, 0, 0);
        }
      }

      if (more) {
        __builtin_amdgcn_s_waitcnt(0x0F70); // vmcnt(0): K in LDS, V in regs
        *(uint4*)(lV0 + nxt * 4096)        = va;
        *(uint4*)(lV0 + nxt * 4096 + 2048) = vb;
      }
      __syncthreads();                      // one barrier per 64-key tile
      cur = nxt;
    }

    // row sums: lane and lane^32 hold complementary key-halves of q = l31
    float zf = zsum + __shfl_xor(zsum, 32);

    // write out: C rows are q = (r&3)+8*(r>>2)+4*hi, cols d = half*32 + l31
#pragma unroll
    for (int r = 0; r < 16; r++) {
      int qr = (r & 3) + 8 * (r >> 2) + 4 * hi;  // local q row 0..31
      float zr = __shfl(zf, qr, 64);
      float inv = 1.f / zr;
      size_t row = (size_t)(b * 2048 + q0w + qr);
      Y[row * 2048 + h * 64 + l31]      = f2bf(o0[r] * inv);
      Y[row * 2048 + h * 64 + 32 + l31] = f2bf(o1[r] * inv);
    }
  }
}

extern "C" void kernel_launch(void* const* d_in, const int* in_sizes, int n_in,
                              void* d_out, int out_size, void* d_ws, size_t ws_size,
                              hipStream_t stream) {
  const float* x  = (const float*)d_in[0];  // [4096][2048] fp32
  const float* Wq = (const float*)d_in[1];  // [2048][2048]
  const float* Wk = (const float*)d_in[2];  // [2048][512]
  const float* Wv = (const float*)d_in[3];  // [2048][512]
  const float* Wo = (const float*)d_in[4];  // [2048][2048]
  float* outp = (float*)d_out;              // fp32 out

  // workspace (u16 units), ~59 MB peak
  u16* xb    = (u16*)d_ws;             // [4096][2048]   8388608
  u16* WqkvT = xb + 8388608;           // [3072][2048]   6291456
  u16* QKV   = WqkvT + 6291456;        // [4096][3072]  12582912
  u16* Vt    = QKV + 12582912;         // [512][4096]    2097152
  u16* Yb    = xb;                     // reuse (xb dead after QKV gemm)
  u16* WoT   = WqkvT;                  // reuse (WqkvT dead after QKV gemm)

  // x -> bf16
  cvt_bf16_f32<<<4096, 256, 0, stream>>>(x, xb, 1048576);

  // weights -> transposed bf16, stacked [Wq^T; Wk^T; Wv^T]
  transpose_cvt<<<dim3(64, 64), 256, 0, stream>>>(Wq, WqkvT, 2048, 2048);
  transpose_cvt<<<dim3(16, 64), 256, 0, stream>>>(Wk, WqkvT + (size_t)2048 * 2048, 2048, 512);
  transpose_cvt<<<dim3(16, 64), 256, 0, stream>>>(Wv, WqkvT + (size_t)2560 * 2048, 2048, 512);

  // fused QKV projection: [4096,2048] x [2048,3072] -> [4096,3072]
  gemm128<u16><<<dim3(24, 32), 256, 0, stream>>>(xb, WqkvT, QKV, 4096, 3072, 2048);

  // RoPE on Q and K slices (in place, strided)
  rope_k<<<(4096 * 1024) / 256, 256, 0, stream>>>(QKV, 3072, 2048, 4096 * 1024);
  rope_k<<<(4096 * 256) / 256, 256, 0, stream>>>(QKV + 2048, 3072, 512, 4096 * 256);

  // V slice -> V^T
  transpose_sl<<<dim3(16, 128), 256, 0, stream>>>(QKV + 2560, 3072, Vt, 4096, 512);

  // attention v3 (KVBLK=64, paired strips) -> Yb
  attn64<<<dim3(8, 64), 256, 0, stream>>>(QKV, Vt, Yb);

  // Wo -> WoT, output projection -> fp32 d_out
  transpose_cvt<<<dim3(64, 64), 256, 0, stream>>>(Wo, WoT, 2048, 2048);
  gemm128<float><<<dim3(16, 32), 256, 0, stream>>>(Yb, WoT, outp, 4096, 2048, 2048);
}

// Round 5
// 329.553 us; speedup vs baseline: 1.3031x; 1.0664x over previous
//
#include <hip/hip_runtime.h>

using u16 = unsigned short;
using u32 = unsigned int;

typedef __attribute__((ext_vector_type(8))) __bf16 bf16x8;
typedef __attribute__((ext_vector_type(4))) float f32x4;
typedef __attribute__((ext_vector_type(16))) float f32x16;

#define DEVI __device__ __forceinline__

DEVI float bf2f(u16 u) {
  union { u32 i; float f; } v; v.i = ((u32)u) << 16; return v.f;
}
DEVI u16 f2bf(float f) {
  union { float f; u32 u; } v; v.f = f;
  u32 u = v.u;
  u32 r = (u + 0x7fffu + ((u >> 16) & 1u)) >> 16;
  return (u16)r;
}
// pack two f32 -> one u32 of 2x bf16 (compiler emits v_cvt_pk_bf16_f32)
DEVI u32 pkbf(float a, float b) {
  union { __bf16 h[2]; u32 u; } t;
  t.h[0] = (__bf16)a; t.h[1] = (__bf16)b;
  return t.u;
}

// async global->LDS, 16B per lane. LDS dest = wave-uniform base + lane*16.
DEVI void gload16(const u16* g, u16* l) {
  __builtin_amdgcn_global_load_lds(
      (const __attribute__((address_space(1))) void*)g,
      (__attribute__((address_space(3))) void*)l, 16, 0, 0);
}

// ---------------- cvt x: fp32 -> bf16, 8 elems/thread ----------------
__global__ __launch_bounds__(256) void cvt_bf16_f32(const float* __restrict__ in,
                                                    u16* __restrict__ out, int n8) {
  int i = blockIdx.x * 256 + threadIdx.x;
  if (i >= n8) return;
  const float4* fin = (const float4*)in;
  float4 a = fin[i * 2], b = fin[i * 2 + 1];
  u16 o[8] = {f2bf(a.x), f2bf(a.y), f2bf(a.z), f2bf(a.w),
              f2bf(b.x), f2bf(b.y), f2bf(b.z), f2bf(b.w)};
  ((uint4*)out)[i] = *(const uint4*)o;
}

// ------- 64x64 vectorized transpose+convert: in[R][Cc] f32 -> out[Cc][R] bf16 -------
// Load: uint4-width (4x float4/thread). LDS [64][72] (144B row stride, 16B-aligned).
// Store: lane = column -> LDS gather is 2-way-free (bank = c>>1); 2 uint4 stores/thread.
__global__ __launch_bounds__(256) void transpose_cvt64(const float* __restrict__ in,
                                                       u16* __restrict__ out,
                                                       int R, int Cc) {
  __shared__ u16 tile[64][72];
  int c0 = blockIdx.x * 64, r0 = blockIdx.y * 64;
  int t = threadIdx.x;
  {
    int row = t >> 2, part = t & 3;
    const float* src = in + (size_t)(r0 + row) * Cc + c0 + part * 16;
    float4 f0 = ((const float4*)src)[0];
    float4 f1 = ((const float4*)src)[1];
    float4 f2 = ((const float4*)src)[2];
    float4 f3 = ((const float4*)src)[3];
    u16 v[16] = {f2bf(f0.x), f2bf(f0.y), f2bf(f0.z), f2bf(f0.w),
                 f2bf(f1.x), f2bf(f1.y), f2bf(f1.z), f2bf(f1.w),
                 f2bf(f2.x), f2bf(f2.y), f2bf(f2.z), f2bf(f2.w),
                 f2bf(f3.x), f2bf(f3.y), f2bf(f3.z), f2bf(f3.w)};
    *(uint4*)&tile[row][part * 16]     = ((const uint4*)v)[0];
    *(uint4*)&tile[row][part * 16 + 8] = ((const uint4*)v)[1];
  }
  __syncthreads();
  {
    int c = t & 63, rq = t >> 6;
    u16 v[16];
#pragma unroll
    for (int i = 0; i < 16; i++) v[i] = tile[rq * 16 + i][c];
    u16* dst = out + (size_t)(c0 + c) * R + r0 + rq * 16;
    ((uint4*)dst)[0] = ((const uint4*)v)[0];
    ((uint4*)dst)[1] = ((const uint4*)v)[1];
  }
}

// ---- 64x64 vectorized bf16 transpose with input row-stride (V slice) ----
__global__ __launch_bounds__(256) void transpose_sl64(const u16* __restrict__ in, int ldin,
                                                      u16* __restrict__ out,
                                                      int R, int Cc) {
  __shared__ u16 tile[64][72];
  int c0 = blockIdx.x * 64, r0 = blockIdx.y * 64;
  int t = threadIdx.x;
  {
    int row = t >> 2, part = t & 3;
    const u16* src = in + (size_t)(r0 + row) * ldin + c0 + part * 16;
    uint4 a = ((const uint4*)src)[0];
    uint4 b = ((const uint4*)src)[1];
    *(uint4*)&tile[row][part * 16]     = a;
    *(uint4*)&tile[row][part * 16 + 8] = b;
  }
  __syncthreads();
  {
    int c = t & 63, rq = t >> 6;
    u16 v[16];
#pragma unroll
    for (int i = 0; i < 16; i++) v[i] = tile[rq * 16 + i][c];
    u16* dst = out + (size_t)(c0 + c) * R + r0 + rq * 16;
    ((uint4*)dst)[0] = ((const uint4*)v)[0];
    ((uint4*)dst)[1] = ((const uint4*)v)[1];
  }
}

// ------------- RoPE, vectorized: 8 consecutive d per thread, 16B ld/st -------------
// Pair (d, d+32); angle walked iteratively: ang_{i+1} = ang_i * 2^(-log2(theta)/32).
// scale is folded into (c,s): Q pass uses (1/sqrt(64))*log2(e) so attention can do
// exp2(S) with no per-element multiply; K pass uses 1.0.
__global__ __launch_bounds__(256) void rope_v(u16* __restrict__ X, int ld, int h4shift,
                                              float scale, int total) {
  int idx = blockIdx.x * 256 + threadIdx.x;
  if (idx >= total) return;
  int hq   = idx & ((1 << h4shift) - 1);
  int row  = idx >> h4shift;
  int head = hq >> 2;
  int d0   = (hq & 3) * 8;
  int tpos = row & 2047;
  size_t base = (size_t)row * ld + head * 64 + d0;
  uint4 lo = *(const uint4*)(X + base);
  uint4 hi = *(const uint4*)(X + base + 32);
  const u16* lp = (const u16*)&lo;
  const u16* hp = (const u16*)&hi;
  float ang = (float)tpos * exp2f(-(float)d0 * 0.59161152f);  // 500000^(-d/32)
  u16 o0[8], o1[8];
#pragma unroll
  for (int i = 0; i < 8; i++) {
    float s, c;
    __sincosf(ang, &s, &c);
    s *= scale; c *= scale;
    float x0 = bf2f(lp[i]);
    float x1 = bf2f(hp[i]);
    o0[i] = f2bf(x0 * c - x1 * s);
    o1[i] = f2bf(x1 * c + x0 * s);
    ang *= 0.6636011f;  // 2^(-0.59161152)
  }
  *(uint4*)(X + base)      = *(const uint4*)o0;
  *(uint4*)(X + base + 32) = *(const uint4*)o1;
}

// ---- GEMM: C[M,N] = A[M,K] * Bt[N,K]^T, 128x128 tile, BK=32 ----
// v4: T3-minimum 2-phase pipeline — double-buffered LDS, next K-step's
// global_load_lds issued BEFORE current step's compute, single
// vmcnt(0)+barrier per step (was: serial stage -> drain -> barrier -> compute).
DEVI void cstore(u16* C, size_t idx, float v)   { C[idx] = f2bf(v); }
DEVI void cstore(float* C, size_t idx, float v) { C[idx] = v; }

template <typename TO>
__global__ __launch_bounds__(256) void gemm128(const u16* __restrict__ A,
                                               const u16* __restrict__ Bt,
                                               TO* __restrict__ C,
                                               int M, int N, int K) {
  __shared__ u16 As[2 * 128 * 32];
  __shared__ u16 Bs[2 * 128 * 32];
  int tid = threadIdx.x, wid = tid >> 6, lane = tid & 63;
  int quad = lane >> 4, l15 = lane & 15;
  int m0 = blockIdx.y * 128, n0 = blockIdx.x * 128;
  int wm = (wid >> 1) * 64, wn = (wid & 1) * 64;

  int r0s = wid * 16 + (lane >> 2);
  int r1s = 64 + wid * 16 + (lane >> 2);
  int cblk = lane & 3;
  int cs0 = (cblk ^ ((r0s >> 1) & 3)) * 8;
  int cs1 = (cblk ^ ((r1s >> 1) & 3)) * 8;
  u16* lA0 = As + wid * 512 + lane * 8;
  u16* lA1 = As + (4 + wid) * 512 + lane * 8;
  u16* lB0 = Bs + wid * 512 + lane * 8;
  u16* lB1 = Bs + (4 + wid) * 512 + lane * 8;
  const u16* gA0 = A + (size_t)(m0 + r0s) * K + cs0;
  const u16* gA1 = A + (size_t)(m0 + r1s) * K + cs1;
  const u16* gB0 = Bt + (size_t)(n0 + r0s) * K + cs0;
  const u16* gB1 = Bt + (size_t)(n0 + r1s) * K + cs1;

  f32x4 acc[4][4];
  for (int i = 0; i < 4; i++)
    for (int j = 0; j < 4; j++) acc[i][j] = f32x4{0.f, 0.f, 0.f, 0.f};

  // prologue: stage K-step 0 into buf 0
  gload16(gA0, lA0);
  gload16(gA1, lA1);
  gload16(gB0, lB0);
  gload16(gB1, lB1);
  __builtin_amdgcn_s_waitcnt(0x0F70);  // vmcnt(0)
  __syncthreads();

  int cur = 0;
  for (int k0 = 0; k0 < K; k0 += 32) {
    int nb = cur ^ 1;
    if (k0 + 32 < K) {                 // prefetch next K-step into other buf
      gload16(gA0 + k0 + 32, lA0 + nb * 4096);
      gload16(gA1 + k0 + 32, lA1 + nb * 4096);
      gload16(gB0 + k0 + 32, lB0 + nb * 4096);
      gload16(gB1 + k0 + 32, lB1 + nb * 4096);
    }
    const u16* Ab = As + cur * 4096;
    const u16* Bb = Bs + cur * 4096;
    bf16x8 af[4], bf_[4];
    for (int mi = 0; mi < 4; mi++) {
      int row = wm + mi * 16 + l15;
      af[mi] = *(const bf16x8*)(Ab + row * 32 + ((quad ^ ((row >> 1) & 3)) * 8));
    }
    for (int ni = 0; ni < 4; ni++) {
      int row = wn + ni * 16 + l15;
      bf_[ni] = *(const bf16x8*)(Bb + row * 32 + ((quad ^ ((row >> 1) & 3)) * 8));
    }
    for (int mi = 0; mi < 4; mi++)
      for (int ni = 0; ni < 4; ni++)
        acc[mi][ni] = __builtin_amdgcn_mfma_f32_16x16x32_bf16(af[mi], bf_[ni], acc[mi][ni], 0, 0, 0);
    __builtin_amdgcn_s_waitcnt(0x0F70);  // vmcnt(0): prefetch landed
    __syncthreads();                     // one barrier per K-step
    cur = nb;
  }
  for (int mi = 0; mi < 4; mi++)
    for (int ni = 0; ni < 4; ni++)
      for (int r = 0; r < 4; r++) {
        int row = m0 + wm + mi * 16 + quad * 4 + r;
        int col = n0 + wn + ni * 16 + l15;
        cstore(C, (size_t)row * N + col, acc[mi][ni][r]);
      }
}

// ---------------- Flash attention: KVBLK=64 + causal pairing (round-4 verified) ----
// Only change vs round 4: softmax scale (1/sqrt(64))*log2(e) is pre-folded into Q
// by rope_v, so the numerator is exp2(S) directly (saves 16 v_mul per subtile).
__global__ __launch_bounds__(256) void attn64(const u16* __restrict__ QKV,
                                              const u16* __restrict__ Vt,
                                              u16* __restrict__ Y) {
  __shared__ u16 Ks[2 * 64 * 64];   // 2 bufs, [key][d], granule-swizzled
  __shared__ u16 Vst[2 * 64 * 64];  // 2 bufs, [d][key], granule-swizzled

  int tid = threadIdx.x, wid = tid >> 6, lane = tid & 63;
  int l31 = lane & 31, hi = lane >> 5;
  int bh = blockIdx.y, b = bh >> 5, h = bh & 31, kvh = h >> 2;
  int p = blockIdx.x;                       // pair index 0..7

  // K staging (global_load_lds, linear dest + inverse-swizzled src)
  int kr  = wid * 8 + (lane >> 3);
  int kgn = lane & 7;
  const u16* gK0 = QKV + (size_t)(b * 2048 + kr) * 3072 + 2048 + kvh * 64
                 + ((kgn ^ (kr & 7)) * 8);
  u16* lK0 = Ks + wid * 512 + lane * 8;     // +buf*4096; +2048 for rows+32

  // V staging (reg-staged, swizzled ds_write)
  int vr = tid >> 3, vg = tid & 7;
  const u16* gV0 = Vt + (size_t)(kvh * 64 + vr) * 4096 + b * 2048 + vg * 8;
  u16* lV0 = Vst + vr * 64 + ((vg ^ (vr & 7)) * 8);  // +buf*4096; +2048 for d+32

  for (int pass = 0; pass < 2; pass++) {
    int j   = pass ? (15 - p) : p;          // q-strip index 0..15
    int q0w = j * 128 + wid * 32;
    int qg  = q0w + l31;                    // this lane's q row

    // Q fragments (RoPE'd + scale-folded in place): Q[qg][dh*16 + hi*8 + i]
    bf16x8 qf[4];
    {
      const u16* qp = QKV + (size_t)(b * 2048 + qg) * 3072 + h * 64 + hi * 8;
#pragma unroll
      for (int dh = 0; dh < 4; dh++) qf[dh] = *(const bf16x8*)(qp + dh * 16);
    }

    f32x16 o0, o1;
#pragma unroll
    for (int i = 0; i < 16; i++) { o0[i] = 0.f; o1[i] = 0.f; }
    float zsum = 0.f;

    int nkt = 2 * (j + 1);                  // 64-key tiles covering 0..j*128+127

    // prologue: stage tile 0 into buf 0
    {
      uint4 va = *(const uint4*)(gV0);
      uint4 vb = *(const uint4*)(gV0 + 32 * 4096);
      gload16(gK0, lK0);
      gload16(gK0 + 32 * 3072, lK0 + 2048);
      __builtin_amdgcn_s_waitcnt(0x0F70);   // vmcnt(0)
      *(uint4*)(lV0)        = va;
      *(uint4*)(lV0 + 2048) = vb;
    }
    __syncthreads();

    int cur = 0;
    for (int kt = 0; kt < nkt; kt++) {
      int kbase = kt * 64;
      int nxt = cur ^ 1;
      bool more = (kt + 1 < nkt);
      uint4 va, vb;
      if (more) {                           // issue next tile's loads early
        size_t ko = (size_t)(kbase + 64);
        va = *(const uint4*)(gV0 + ko);
        vb = *(const uint4*)(gV0 + 32 * 4096 + ko);
        gload16(gK0 + ko * 3072, lK0 + nxt * 4096);
        gload16(gK0 + ko * 3072 + 32 * 3072, lK0 + nxt * 4096 + 2048);
      }

      const u16* Kb = Ks + cur * 4096;
      const u16* Vb = Vst + cur * 4096;
#pragma unroll
      for (int sub = 0; sub < 2; sub++) {
        int kb = kbase + sub * 32;
        if (kb > q0w) break;                // wave-uniform causal skip

        // S^T[key][q] over keys kb..kb+31 (already scaled by 1/8*log2e via Q)
        f32x16 s;
#pragma unroll
        for (int i = 0; i < 16; i++) s[i] = 0.f;
#pragma unroll
        for (int dh = 0; dh < 4; dh++) {
          int g = (dh * 2 + hi) ^ (l31 & 7);
          bf16x8 kf = *(const bf16x8*)(Kb + (sub * 32 + l31) * 64 + g * 8);
          s = __builtin_amdgcn_mfma_f32_32x32x16_bf16(kf, qf[dh], s, 0, 0, 0);
        }

        float pb[16];
        if (kb < q0w) {                     // full subtile: no mask needed
#pragma unroll
          for (int r = 0; r < 16; r++) {
            float pv = exp2f(s[r]);
            zsum += pv;
            pb[r] = pv;
          }
        } else {                            // diagonal subtile (kb == q0w)
#pragma unroll
          for (int r = 0; r < 16; r++) {
            int key = kb + (r & 3) + 8 * (r >> 2) + 4 * hi;
            float pv = (key <= qg) ? exp2f(s[r]) : 0.f;
            zsum += pv;
            pb[r] = pv;
          }
        }

        // P -> PV A-fragment: cvt_pk + permlane32_swap (verified round 3)
#pragma unroll
        for (int kk = 0; kk < 2; kk++) {
          const float* pp = pb + kk * 8;
          u32 a01 = pkbf(pp[0], pp[1]);
          u32 a23 = pkbf(pp[2], pp[3]);
          u32 a45 = pkbf(pp[4], pp[5]);
          u32 a67 = pkbf(pp[6], pp[7]);
          asm volatile("v_permlane32_swap_b32 %0, %1" : "+v"(a01), "+v"(a45));
          asm volatile("v_permlane32_swap_b32 %0, %1" : "+v"(a23), "+v"(a67));
          union { u32 w[4]; bf16x8 v; } pf;
          pf.w[0] = a01; pf.w[1] = a23; pf.w[2] = a45; pf.w[3] = a67;
          int kgr = sub * 4 + kk * 2 + hi;  // key granule within 64-key tile
          const u16* vp = Vb + l31 * 64 + ((kgr ^ (l31 & 7)) * 8);
          bf16x8 v0 = *(const bf16x8*)(vp);
          bf16x8 v1 = *(const bf16x8*)(vp + 2048);   // d+32 rows
          o0 = __builtin_amdgcn_mfma_f32_32x32x16_bf16(pf.v, v0, o0, 0, 0, 0);
          o1 = __builtin_amdgcn_mfma_f32_32x32x16_bf16(pf.v, v1, o1, 0, 0, 0);
        }
      }

      if (more) {
        __builtin_amdgcn_s_waitcnt(0x0F70); // vmcnt(0): K in LDS, V in regs
        *(uint4*)(lV0 + nxt * 4096)        = va;
        *(uint4*)(lV0 + nxt * 4096 + 2048) = vb;
      }
      __syncthreads();                      // one barrier per 64-key tile
      cur = nxt;
    }

    // row sums: lane and lane^32 hold complementary key-halves of q = l31
    float zf = zsum + __shfl_xor(zsum, 32);

    // write out: C rows are q = (r&3)+8*(r>>2)+4*hi, cols d = half*32 + l31
#pragma unroll
    for (int r = 0; r < 16; r++) {
      int qr = (r & 3) + 8 * (r >> 2) + 4 * hi;  // local q row 0..31
      float zr = __shfl(zf, qr, 64);
      float inv = 1.f / zr;
      size_t row = (size_t)(b * 2048 + q0w + qr);
      Y[row * 2048 + h * 64 + l31]      = f2bf(o0[r] * inv);
      Y[row * 2048 + h * 64 + 32 + l31] = f2bf(o1[r] * inv);
    }
  }
}

extern "C" void kernel_launch(void* const* d_in, const int* in_sizes, int n_in,
                              void* d_out, int out_size, void* d_ws, size_t ws_size,
                              hipStream_t stream) {
  const float* x  = (const float*)d_in[0];  // [4096][2048] fp32
  const float* Wq = (const float*)d_in[1];  // [2048][2048]
  const float* Wk = (const float*)d_in[2];  // [2048][512]
  const float* Wv = (const float*)d_in[3];  // [2048][512]
  const float* Wo = (const float*)d_in[4];  // [2048][2048]
  float* outp = (float*)d_out;              // fp32 out

  // workspace (u16 units), ~59 MB peak
  u16* xb    = (u16*)d_ws;             // [4096][2048]   8388608
  u16* WqkvT = xb + 8388608;           // [3072][2048]   6291456
  u16* QKV   = WqkvT + 6291456;        // [4096][3072]  12582912
  u16* Vt    = QKV + 12582912;         // [512][4096]    2097152
  u16* Yb    = xb;                     // reuse (xb dead after QKV gemm)
  u16* WoT   = WqkvT;                  // reuse (WqkvT dead after QKV gemm)

  // x -> bf16
  cvt_bf16_f32<<<4096, 256, 0, stream>>>(x, xb, 1048576);

  // weights -> transposed bf16, stacked [Wq^T; Wk^T; Wv^T]
  transpose_cvt64<<<dim3(32, 32), 256, 0, stream>>>(Wq, WqkvT, 2048, 2048);
  transpose_cvt64<<<dim3(8, 32), 256, 0, stream>>>(Wk, WqkvT + (size_t)2048 * 2048, 2048, 512);
  transpose_cvt64<<<dim3(8, 32), 256, 0, stream>>>(Wv, WqkvT + (size_t)2560 * 2048, 2048, 512);

  // fused QKV projection: [4096,2048] x [2048,3072] -> [4096,3072]
  gemm128<u16><<<dim3(24, 32), 256, 0, stream>>>(xb, WqkvT, QKV, 4096, 3072, 2048);

  // RoPE (vectorized, in place). Q pass folds (1/sqrt(64))*log2(e) for attention.
  rope_v<<<2048, 256, 0, stream>>>(QKV, 3072, 7, 0.18033688f, 4096 * 128);
  rope_v<<<512, 256, 0, stream>>>(QKV + 2048, 3072, 5, 1.0f, 4096 * 32);

  // V slice -> V^T
  transpose_sl64<<<dim3(8, 64), 256, 0, stream>>>(QKV + 2560, 3072, Vt, 4096, 512);

  // attention (KVBLK=64, paired strips) -> Yb
  attn64<<<dim3(8, 64), 256, 0, stream>>>(QKV, Vt, Yb);

  // Wo -> WoT, output projection -> fp32 d_out
  transpose_cvt64<<<dim3(32, 32), 256, 0, stream>>>(Wo, WoT, 2048, 2048);
  gemm128<float><<<dim3(16, 32), 256, 0, stream>>>(Yb, WoT, outp, 4096, 2048, 2048);
}

// Round 6
// 322.546 us; speedup vs baseline: 1.3314x; 1.0217x over previous
//
#include <hip/hip_runtime.h>

using u16 = unsigned short;
using u32 = unsigned int;

typedef __attribute__((ext_vector_type(8))) __bf16 bf16x8;
typedef __attribute__((ext_vector_type(4))) float f32x4;
typedef __attribute__((ext_vector_type(16))) float f32x16;

#define DEVI __device__ __forceinline__

DEVI float bf2f(u16 u) {
  union { u32 i; float f; } v; v.i = ((u32)u) << 16; return v.f;
}
DEVI u16 f2bf(float f) {
  union { float f; u32 u; } v; v.f = f;
  u32 u = v.u;
  u32 r = (u + 0x7fffu + ((u >> 16) & 1u)) >> 16;
  return (u16)r;
}
// pack two f32 -> one u32 of 2x bf16 (compiler emits v_cvt_pk_bf16_f32)
DEVI u32 pkbf(float a, float b) {
  union { __bf16 h[2]; u32 u; } t;
  t.h[0] = (__bf16)a; t.h[1] = (__bf16)b;
  return t.u;
}

// async global->LDS, 16B per lane. LDS dest = wave-uniform base + lane*16.
DEVI void gload16(const u16* g, u16* l) {
  __builtin_amdgcn_global_load_lds(
      (const __attribute__((address_space(1))) void*)g,
      (__attribute__((address_space(3))) void*)l, 16, 0, 0);
}

// ---------------- cvt x: fp32 -> bf16, 8 elems/thread ----------------
__global__ __launch_bounds__(256) void cvt_bf16_f32(const float* __restrict__ in,
                                                    u16* __restrict__ out, int n8) {
  int i = blockIdx.x * 256 + threadIdx.x;
  if (i >= n8) return;
  const float4* fin = (const float4*)in;
  float4 a = fin[i * 2], b = fin[i * 2 + 1];
  u16 o[8] = {f2bf(a.x), f2bf(a.y), f2bf(a.z), f2bf(a.w),
              f2bf(b.x), f2bf(b.y), f2bf(b.z), f2bf(b.w)};
  ((uint4*)out)[i] = *(const uint4*)o;
}

// ------- 64x64 transpose+convert body: in[R][Cc] f32 -> out[Cc][R] bf16 -------
DEVI void tcvt64_body(const float* in, u16* out, int R, int Cc, int c0, int r0, int t,
                      u16 (*tile)[72]) {
  {
    int row = t >> 2, part = t & 3;
    const float* src = in + (size_t)(r0 + row) * Cc + c0 + part * 16;
    float4 f0 = ((const float4*)src)[0];
    float4 f1 = ((const float4*)src)[1];
    float4 f2 = ((const float4*)src)[2];
    float4 f3 = ((const float4*)src)[3];
    u16 v[16] = {f2bf(f0.x), f2bf(f0.y), f2bf(f0.z), f2bf(f0.w),
                 f2bf(f1.x), f2bf(f1.y), f2bf(f1.z), f2bf(f1.w),
                 f2bf(f2.x), f2bf(f2.y), f2bf(f2.z), f2bf(f2.w),
                 f2bf(f3.x), f2bf(f3.y), f2bf(f3.z), f2bf(f3.w)};
    *(uint4*)&tile[row][part * 16]     = ((const uint4*)v)[0];
    *(uint4*)&tile[row][part * 16 + 8] = ((const uint4*)v)[1];
  }
  __syncthreads();
  {
    int c = t & 63, rq = t >> 6;
    u16 v[16];
#pragma unroll
    for (int i = 0; i < 16; i++) v[i] = tile[rq * 16 + i][c];
    u16* dst = out + (size_t)(c0 + c) * R + r0 + rq * 16;
    ((uint4*)dst)[0] = ((const uint4*)v)[0];
    ((uint4*)dst)[1] = ((const uint4*)v)[1];
  }
}

__global__ __launch_bounds__(256) void transpose_cvt64(const float* __restrict__ in,
                                                       u16* __restrict__ out,
                                                       int R, int Cc) {
  __shared__ u16 tile[64][72];
  tcvt64_body(in, out, R, Cc, blockIdx.x * 64, blockIdx.y * 64, threadIdx.x, tile);
}

// ---- fused Wq/Wk/Wv transpose (one launch): grid.x slices select the matrix ----
__global__ __launch_bounds__(256) void transpose_wqkv(const float* __restrict__ Wq,
                                                      const float* __restrict__ Wk,
                                                      const float* __restrict__ Wv,
                                                      u16* __restrict__ out) {
  __shared__ u16 tile[64][72];
  int bx = blockIdx.x;
  const float* in;
  u16* dst;
  int Cc, c0;
  if (bx < 32)      { in = Wq; dst = out;                        Cc = 2048; c0 = bx * 64; }
  else if (bx < 40) { in = Wk; dst = out + (size_t)2048 * 2048;  Cc = 512;  c0 = (bx - 32) * 64; }
  else              { in = Wv; dst = out + (size_t)2560 * 2048;  Cc = 512;  c0 = (bx - 40) * 64; }
  tcvt64_body(in, dst, 2048, Cc, c0, blockIdx.y * 64, threadIdx.x, tile);
}

// ---- 64x64 vectorized bf16 transpose with input row-stride (V slice) ----
__global__ __launch_bounds__(256) void transpose_sl64(const u16* __restrict__ in, int ldin,
                                                      u16* __restrict__ out,
                                                      int R, int Cc) {
  __shared__ u16 tile[64][72];
  int c0 = blockIdx.x * 64, r0 = blockIdx.y * 64;
  int t = threadIdx.x;
  {
    int row = t >> 2, part = t & 3;
    const u16* src = in + (size_t)(r0 + row) * ldin + c0 + part * 16;
    uint4 a = ((const uint4*)src)[0];
    uint4 b = ((const uint4*)src)[1];
    *(uint4*)&tile[row][part * 16]     = a;
    *(uint4*)&tile[row][part * 16 + 8] = b;
  }
  __syncthreads();
  {
    int c = t & 63, rq = t >> 6;
    u16 v[16];
#pragma unroll
    for (int i = 0; i < 16; i++) v[i] = tile[rq * 16 + i][c];
    u16* dst = out + (size_t)(c0 + c) * R + r0 + rq * 16;
    ((uint4*)dst)[0] = ((const uint4*)v)[0];
    ((uint4*)dst)[1] = ((const uint4*)v)[1];
  }
}

// ------------- RoPE, vectorized + fused Q/K passes in one launch -------------
// Q slice (idx < NQ): scale (1/sqrt(64))*log2(e) folded in. K slice: scale 1.
DEVI void rope_body(u16* X, int h4shift, float scale, int idx) {
  int hq   = idx & ((1 << h4shift) - 1);
  int row  = idx >> h4shift;
  int head = hq >> 2;
  int d0   = (hq & 3) * 8;
  int tpos = row & 2047;
  size_t base = (size_t)row * 3072 + head * 64 + d0;
  uint4 lo = *(const uint4*)(X + base);
  uint4 hi = *(const uint4*)(X + base + 32);
  const u16* lp = (const u16*)&lo;
  const u16* hp = (const u16*)&hi;
  float ang = (float)tpos * exp2f(-(float)d0 * 0.59161152f);  // 500000^(-d/32)
  u16 o0[8], o1[8];
#pragma unroll
  for (int i = 0; i < 8; i++) {
    float s, c;
    __sincosf(ang, &s, &c);
    s *= scale; c *= scale;
    float x0 = bf2f(lp[i]);
    float x1 = bf2f(hp[i]);
    o0[i] = f2bf(x0 * c - x1 * s);
    o1[i] = f2bf(x1 * c + x0 * s);
    ang *= 0.6636011f;  // 2^(-0.59161152)
  }
  *(uint4*)(X + base)      = *(const uint4*)o0;
  *(uint4*)(X + base + 32) = *(const uint4*)o1;
}

__global__ __launch_bounds__(256) void rope_fused(u16* __restrict__ QKV) {
  const int NQ = 4096 * 128;                // Q: 4096 rows x 32 heads x 4 vec-chunks
  int idx = blockIdx.x * 256 + threadIdx.x;
  if (idx < NQ) rope_body(QKV, 7, 0.18033688f, idx);
  else          rope_body(QKV + 2048, 5, 1.0f, idx - NQ);
}

// ---- GEMM: C[M,N] = A[M,K] * Bt[N,K]^T, 128x128 tile, BK=32, 2-phase dbuf ----
DEVI void cstore(u16* C, size_t idx, float v)   { C[idx] = f2bf(v); }
DEVI void cstore(float* C, size_t idx, float v) { C[idx] = v; }

template <typename TO>
__global__ __launch_bounds__(256) void gemm128(const u16* __restrict__ A,
                                               const u16* __restrict__ Bt,
                                               TO* __restrict__ C,
                                               int M, int N, int K) {
  __shared__ u16 As[2 * 128 * 32];
  __shared__ u16 Bs[2 * 128 * 32];
  int tid = threadIdx.x, wid = tid >> 6, lane = tid & 63;
  int quad = lane >> 4, l15 = lane & 15;
  int m0 = blockIdx.y * 128, n0 = blockIdx.x * 128;
  int wm = (wid >> 1) * 64, wn = (wid & 1) * 64;

  int r0s = wid * 16 + (lane >> 2);
  int r1s = 64 + wid * 16 + (lane >> 2);
  int cblk = lane & 3;
  int cs0 = (cblk ^ ((r0s >> 1) & 3)) * 8;
  int cs1 = (cblk ^ ((r1s >> 1) & 3)) * 8;
  u16* lA0 = As + wid * 512 + lane * 8;
  u16* lA1 = As + (4 + wid) * 512 + lane * 8;
  u16* lB0 = Bs + wid * 512 + lane * 8;
  u16* lB1 = Bs + (4 + wid) * 512 + lane * 8;
  const u16* gA0 = A + (size_t)(m0 + r0s) * K + cs0;
  const u16* gA1 = A + (size_t)(m0 + r1s) * K + cs1;
  const u16* gB0 = Bt + (size_t)(n0 + r0s) * K + cs0;
  const u16* gB1 = Bt + (size_t)(n0 + r1s) * K + cs1;

  f32x4 acc[4][4];
  for (int i = 0; i < 4; i++)
    for (int j = 0; j < 4; j++) acc[i][j] = f32x4{0.f, 0.f, 0.f, 0.f};

  // prologue: stage K-step 0 into buf 0
  gload16(gA0, lA0);
  gload16(gA1, lA1);
  gload16(gB0, lB0);
  gload16(gB1, lB1);
  __builtin_amdgcn_s_waitcnt(0x0F70);  // vmcnt(0)
  __syncthreads();

  int cur = 0;
  for (int k0 = 0; k0 < K; k0 += 32) {
    int nb = cur ^ 1;
    if (k0 + 32 < K) {                 // prefetch next K-step into other buf
      gload16(gA0 + k0 + 32, lA0 + nb * 4096);
      gload16(gA1 + k0 + 32, lA1 + nb * 4096);
      gload16(gB0 + k0 + 32, lB0 + nb * 4096);
      gload16(gB1 + k0 + 32, lB1 + nb * 4096);
    }
    const u16* Ab = As + cur * 4096;
    const u16* Bb = Bs + cur * 4096;
    bf16x8 af[4], bf_[4];
    for (int mi = 0; mi < 4; mi++) {
      int row = wm + mi * 16 + l15;
      af[mi] = *(const bf16x8*)(Ab + row * 32 + ((quad ^ ((row >> 1) & 3)) * 8));
    }
    for (int ni = 0; ni < 4; ni++) {
      int row = wn + ni * 16 + l15;
      bf_[ni] = *(const bf16x8*)(Bb + row * 32 + ((quad ^ ((row >> 1) & 3)) * 8));
    }
    for (int mi = 0; mi < 4; mi++)
      for (int ni = 0; ni < 4; ni++)
        acc[mi][ni] = __builtin_amdgcn_mfma_f32_16x16x32_bf16(af[mi], bf_[ni], acc[mi][ni], 0, 0, 0);
    __builtin_amdgcn_s_waitcnt(0x0F70);  // vmcnt(0): prefetch landed
    __syncthreads();                     // one barrier per K-step
    cur = nb;
  }
  for (int mi = 0; mi < 4; mi++)
    for (int ni = 0; ni < 4; ni++)
      for (int r = 0; r < 4; r++) {
        int row = m0 + wm + mi * 16 + quad * 4 + r;
        int col = n0 + wn + ni * 16 + l15;
        cstore(C, (size_t)row * N + col, acc[mi][ni][r]);
      }
}

// ---------------- Flash attention v5: VALU diet ----------------
// Round-5 counters: MfmaUtil 15.2, VALUBusy 53 -> softmax VALU chain binds.
// (a) S accumulator chain starts from a persistent fzero register vector
//     (first MFMA C-operand) -> kills 16 v_mov zero-inits per subtile.
// (b) z = P*ones via an extra MFMA per kk into zacc (all output cols equal;
//     zacc[r] has the SAME row mapping as o0[r]) -> kills 16 v_add per
//     subtile AND the entire epilogue shuffle reduction. z now sums the
//     bf16-quantized P, exactly consistent with the PV numerator.
// Everything else verbatim from the round-4/5 verified kernel.
__global__ __launch_bounds__(256) void attn64(const u16* __restrict__ QKV,
                                              const u16* __restrict__ Vt,
                                              u16* __restrict__ Y) {
  __shared__ u16 Ks[2 * 64 * 64];   // 2 bufs, [key][d], granule-swizzled
  __shared__ u16 Vst[2 * 64 * 64];  // 2 bufs, [d][key], granule-swizzled

  int tid = threadIdx.x, wid = tid >> 6, lane = tid & 63;
  int l31 = lane & 31, hi = lane >> 5;
  int bh = blockIdx.y, b = bh >> 5, h = bh & 31, kvh = h >> 2;
  int p = blockIdx.x;                       // pair index 0..7

  // K staging (global_load_lds, linear dest + inverse-swizzled src)
  int kr  = wid * 8 + (lane >> 3);
  int kgn = lane & 7;
  const u16* gK0 = QKV + (size_t)(b * 2048 + kr) * 3072 + 2048 + kvh * 64
                 + ((kgn ^ (kr & 7)) * 8);
  u16* lK0 = Ks + wid * 512 + lane * 8;     // +buf*4096; +2048 for rows+32

  // V staging (reg-staged, swizzled ds_write)
  int vr = tid >> 3, vg = tid & 7;
  const u16* gV0 = Vt + (size_t)(kvh * 64 + vr) * 4096 + b * 2048 + vg * 8;
  u16* lV0 = Vst + vr * 64 + ((vg ^ (vr & 7)) * 8);  // +buf*4096; +2048 for d+32

  // persistent zero C-vector and all-ones bf16 B-fragment
  f32x16 fzero;
#pragma unroll
  for (int i = 0; i < 16; i++) fzero[i] = 0.f;
  bf16x8 onesf;
  {
    union { u16 w[8]; bf16x8 v; } t;
#pragma unroll
    for (int i = 0; i < 8; i++) t.w[i] = 0x3F80;  // bf16 1.0
    onesf = t.v;
  }

  for (int pass = 0; pass < 2; pass++) {
    int j   = pass ? (15 - p) : p;          // q-strip index 0..15
    int q0w = j * 128 + wid * 32;
    int qg  = q0w + l31;                    // this lane's q row

    // Q fragments (RoPE'd + scale-folded in place): Q[qg][dh*16 + hi*8 + i]
    bf16x8 qf[4];
    {
      const u16* qp = QKV + (size_t)(b * 2048 + qg) * 3072 + h * 64 + hi * 8;
#pragma unroll
      for (int dh = 0; dh < 4; dh++) qf[dh] = *(const bf16x8*)(qp + dh * 16);
    }

    f32x16 o0, o1, zacc;
#pragma unroll
    for (int i = 0; i < 16; i++) { o0[i] = 0.f; o1[i] = 0.f; zacc[i] = 0.f; }

    int nkt = 2 * (j + 1);                  // 64-key tiles covering 0..j*128+127

    // prologue: stage tile 0 into buf 0
    {
      uint4 va = *(const uint4*)(gV0);
      uint4 vb = *(const uint4*)(gV0 + 32 * 4096);
      gload16(gK0, lK0);
      gload16(gK0 + 32 * 3072, lK0 + 2048);
      __builtin_amdgcn_s_waitcnt(0x0F70);   // vmcnt(0)
      *(uint4*)(lV0)        = va;
      *(uint4*)(lV0 + 2048) = vb;
    }
    __syncthreads();

    int cur = 0;
    for (int kt = 0; kt < nkt; kt++) {
      int kbase = kt * 64;
      int nxt = cur ^ 1;
      bool more = (kt + 1 < nkt);
      uint4 va, vb;
      if (more) {                           // issue next tile's loads early
        size_t ko = (size_t)(kbase + 64);
        va = *(const uint4*)(gV0 + ko);
        vb = *(const uint4*)(gV0 + 32 * 4096 + ko);
        gload16(gK0 + ko * 3072, lK0 + nxt * 4096);
        gload16(gK0 + ko * 3072 + 32 * 3072, lK0 + nxt * 4096 + 2048);
      }

      const u16* Kb = Ks + cur * 4096;
      const u16* Vb = Vst + cur * 4096;
#pragma unroll
      for (int sub = 0; sub < 2; sub++) {
        int kb = kbase + sub * 32;
        if (kb > q0w) break;                // wave-uniform causal skip

        // S^T[key][q] over keys kb..kb+31; chain seeded from fzero (no movs)
        bf16x8 kf0 = *(const bf16x8*)(Kb + (sub * 32 + l31) * 64 + (((0 * 2 + hi) ^ (l31 & 7)) * 8));
        f32x16 s = __builtin_amdgcn_mfma_f32_32x32x16_bf16(kf0, qf[0], fzero, 0, 0, 0);
#pragma unroll
        for (int dh = 1; dh < 4; dh++) {
          int g = (dh * 2 + hi) ^ (l31 & 7);
          bf16x8 kf = *(const bf16x8*)(Kb + (sub * 32 + l31) * 64 + g * 8);
          s = __builtin_amdgcn_mfma_f32_32x32x16_bf16(kf, qf[dh], s, 0, 0, 0);
        }

        float pb[16];
        if (kb < q0w) {                     // full subtile: no mask needed
#pragma unroll
          for (int r = 0; r < 16; r++) pb[r] = exp2f(s[r]);
        } else {                            // diagonal subtile (kb == q0w)
#pragma unroll
          for (int r = 0; r < 16; r++) {
            int key = kb + (r & 3) + 8 * (r >> 2) + 4 * hi;
            pb[r] = (key <= qg) ? exp2f(s[r]) : 0.f;
          }
        }

        // P -> PV A-fragment: cvt_pk + permlane32_swap (verified round 3)
#pragma unroll
        for (int kk = 0; kk < 2; kk++) {
          const float* pp = pb + kk * 8;
          u32 a01 = pkbf(pp[0], pp[1]);
          u32 a23 = pkbf(pp[2], pp[3]);
          u32 a45 = pkbf(pp[4], pp[5]);
          u32 a67 = pkbf(pp[6], pp[7]);
          asm volatile("v_permlane32_swap_b32 %0, %1" : "+v"(a01), "+v"(a45));
          asm volatile("v_permlane32_swap_b32 %0, %1" : "+v"(a23), "+v"(a67));
          union { u32 w[4]; bf16x8 v; } pf;
          pf.w[0] = a01; pf.w[1] = a23; pf.w[2] = a45; pf.w[3] = a67;
          int kgr = sub * 4 + kk * 2 + hi;  // key granule within 64-key tile
          const u16* vp = Vb + l31 * 64 + ((kgr ^ (l31 & 7)) * 8);
          bf16x8 v0 = *(const bf16x8*)(vp);
          bf16x8 v1 = *(const bf16x8*)(vp + 2048);   // d+32 rows
          zacc = __builtin_amdgcn_mfma_f32_32x32x16_bf16(pf.v, onesf, zacc, 0, 0, 0);
          o0 = __builtin_amdgcn_mfma_f32_32x32x16_bf16(pf.v, v0, o0, 0, 0, 0);
          o1 = __builtin_amdgcn_mfma_f32_32x32x16_bf16(pf.v, v1, o1, 0, 0, 0);
        }
      }

      if (more) {
        __builtin_amdgcn_s_waitcnt(0x0F70); // vmcnt(0): K in LDS, V in regs
        *(uint4*)(lV0 + nxt * 4096)        = va;
        *(uint4*)(lV0 + nxt * 4096 + 2048) = vb;
      }
      __syncthreads();                      // one barrier per 64-key tile
      cur = nxt;
    }

    // epilogue: zacc[r] (all cols equal) aligns elementwise with o0/o1[r]
#pragma unroll
    for (int r = 0; r < 16; r++) {
      int qr = (r & 3) + 8 * (r >> 2) + 4 * hi;  // local q row 0..31
      float inv = 1.f / zacc[r];
      size_t row = (size_t)(b * 2048 + q0w + qr);
      Y[row * 2048 + h * 64 + l31]      = f2bf(o0[r] * inv);
      Y[row * 2048 + h * 64 + 32 + l31] = f2bf(o1[r] * inv);
    }
  }
}

extern "C" void kernel_launch(void* const* d_in, const int* in_sizes, int n_in,
                              void* d_out, int out_size, void* d_ws, size_t ws_size,
                              hipStream_t stream) {
  const float* x  = (const float*)d_in[0];  // [4096][2048] fp32
  const float* Wq = (const float*)d_in[1];  // [2048][2048]
  const float* Wk = (const float*)d_in[2];  // [2048][512]
  const float* Wv = (const float*)d_in[3];  // [2048][512]
  const float* Wo = (const float*)d_in[4];  // [2048][2048]
  float* outp = (float*)d_out;              // fp32 out

  // workspace (u16 units), ~59 MB peak
  u16* xb    = (u16*)d_ws;             // [4096][2048]   8388608
  u16* WqkvT = xb + 8388608;           // [3072][2048]   6291456
  u16* QKV   = WqkvT + 6291456;        // [4096][3072]  12582912
  u16* Vt    = QKV + 12582912;         // [512][4096]    2097152
  u16* Yb    = xb;                     // reuse (xb dead after QKV gemm)
  u16* WoT   = WqkvT;                  // reuse (WqkvT dead after QKV gemm)

  // x -> bf16
  cvt_bf16_f32<<<4096, 256, 0, stream>>>(x, xb, 1048576);

  // weights -> transposed bf16, stacked [Wq^T; Wk^T; Wv^T] (one launch)
  transpose_wqkv<<<dim3(48, 32), 256, 0, stream>>>(Wq, Wk, Wv, WqkvT);

  // fused QKV projection: [4096,2048] x [2048,3072] -> [4096,3072]
  gemm128<u16><<<dim3(24, 32), 256, 0, stream>>>(xb, WqkvT, QKV, 4096, 3072, 2048);

  // RoPE (vectorized, Q+K fused; Q pass folds (1/sqrt(64))*log2(e))
  rope_fused<<<2560, 256, 0, stream>>>(QKV);

  // V slice -> V^T
  transpose_sl64<<<dim3(8, 64), 256, 0, stream>>>(QKV + 2560, 3072, Vt, 4096, 512);

  // attention (KVBLK=64, paired strips, VALU diet) -> Yb
  attn64<<<dim3(8, 64), 256, 0, stream>>>(QKV, Vt, Yb);

  // Wo -> WoT, output projection -> fp32 d_out
  transpose_cvt64<<<dim3(32, 32), 256, 0, stream>>>(Wo, WoT, 2048, 2048);
  gemm128<float><<<dim3(16, 32), 256, 0, stream>>>(Yb, WoT, outp, 4096, 2048, 2048);
}